// Round 12
// baseline (9348.508 us; speedup 1.0000x reference)
//
#include <hip/hip_runtime.h>
#include <hip/hip_bf16.h>

// Problem constants
#define BB 32     // batch
#define TT 512    // time
#define AA 512    // acoustic dim
#define EE 256    // emb dim
#define HH 320    // hidden
#define VV 8192   // vocab
#define KIN 768   // A+E
#define G4 1280   // 4*H

#define RB 4      // batches per rec block (8 blocks, no inter-block sync)

typedef __bf16 bf16x8v __attribute__((ext_vector_type(8)));
typedef float f32x4 __attribute__((ext_vector_type(4)));

__device__ __forceinline__ float fsigm(float x) { return 1.f / (1.f + __expf(-x)); }
__device__ __forceinline__ float ftanh(float x) { return 2.f / (1.f + __expf(-2.f * x)) - 1.f; }
__device__ __forceinline__ unsigned short f2bf(float f) {
    __hip_bfloat16 h = __float2bfloat16(f);
    return *(unsigned short*)&h;
}

// ---------------- Stage A: X[r=t*B+b][j] = tanh(concat(a,e) . W_in[j,:] + b_in[j]) ----------------
__global__ __launch_bounds__(320) void stage_x(const float* __restrict__ ac,
                                               const int* __restrict__ tok,
                                               const float* __restrict__ emb,
                                               const float* __restrict__ Win,
                                               const float* __restrict__ bin,
                                               float* __restrict__ X) {
    __shared__ float xs[8][KIN];
    const int r0 = blockIdx.x * 8;
    const int tid = threadIdx.x;
    for (int rr = 0; rr < 8; ++rr) {
        const int r = r0 + rr;
        const int t = r >> 5;
        const int b = r & 31;
        const int tk = tok[b * TT + t];
        const float4* ac4  = (const float4*)(ac + ((size_t)b * TT + t) * AA);
        const float4* emb4 = (const float4*)(emb + (size_t)tk * EE);
        float4* xs4 = (float4*)&xs[rr][0];
        for (int k4 = tid; k4 < KIN / 4; k4 += 320) {
            float4 v;
            if (k4 < AA / 4) v = ac4[k4];
            else if (tk == 0) v = make_float4(0.f, 0.f, 0.f, 0.f);
            else v = emb4[k4 - AA / 4];
            xs4[k4] = v;
        }
    }
    __syncthreads();
    const int j = tid;
    float acc[8];
    const float bj = bin[j];
#pragma unroll
    for (int rr = 0; rr < 8; ++rr) acc[rr] = bj;
    const float4* w4 = (const float4*)(Win + (size_t)j * KIN);
#pragma unroll 4
    for (int k4 = 0; k4 < KIN / 4; ++k4) {
        const float4 wv = w4[k4];
#pragma unroll
        for (int rr = 0; rr < 8; ++rr) {
            const float4 xv = ((const float4*)&xs[rr][0])[k4];
            acc[rr] += wv.x * xv.x + wv.y * xv.y + wv.z * xv.z + wv.w * xv.w;
        }
    }
#pragma unroll
    for (int rr = 0; rr < 8; ++rr)
        X[(size_t)(r0 + rr) * HH + j] = tanhf(acc[rr]);
}

// ---------------- Stage B: G[r=t*B+b][j] = X[r,:] . W_ih[j,:] + b_ih[j] + b_hh[j] ----------------
__global__ __launch_bounds__(256) void stage_gin(const float* __restrict__ X,
                                                 const float* __restrict__ Wih,
                                                 const float* __restrict__ bih,
                                                 const float* __restrict__ bhh,
                                                 float* __restrict__ G) {
    __shared__ float xs[8][HH];
    const int r0 = blockIdx.x * 8;
    const int tid = threadIdx.x;
    {
        const float4* src = (const float4*)(X + (size_t)r0 * HH);
        float4* dst = (float4*)&xs[0][0];
        for (int k4 = tid; k4 < 8 * HH / 4; k4 += 256) dst[k4] = src[k4];
    }
    __syncthreads();
    for (int p5 = 0; p5 < 5; ++p5) {
        const int j = tid + 256 * p5;   // 0..1279
        const float bias = bih[j] + bhh[j];
        float acc[8];
#pragma unroll
        for (int rr = 0; rr < 8; ++rr) acc[rr] = bias;
        const float4* w4 = (const float4*)(Wih + (size_t)j * HH);
#pragma unroll 4
        for (int k4 = 0; k4 < HH / 4; ++k4) {
            const float4 wv = w4[k4];
#pragma unroll
            for (int rr = 0; rr < 8; ++rr) {
                const float4 xv = ((const float4*)&xs[rr][0])[k4];
                acc[rr] += wv.x * xv.x + wv.y * xv.y + wv.z * xv.z + wv.w * xv.w;
            }
        }
#pragma unroll
        for (int rr = 0; rr < 8; ++rr)
            G[(size_t)(r0 + rr) * G4 + j] = acc[rr];
    }
}

// ---------------- Wout fp32 -> bf16 (row-major) ----------------
__global__ __launch_bounds__(256) void wcvt(const float* __restrict__ src,
                                            unsigned short* __restrict__ dst, int n4) {
    const int i = blockIdx.x * 256 + threadIdx.x;
    if (i < n4) {
        const float4 v = ((const float4*)src)[i];
        ushort4 o;
        o.x = f2bf(v.x); o.y = f2bf(v.y); o.z = f2bf(v.z); o.w = f2bf(v.w);
        ((ushort4*)dst)[i] = o;
    }
}

// ---------------- Whh fp32 -> bf16, permuted to frag-contiguous [tile(80)][kc(10)][lane(64)][8] ----------------
// dst[((tile*10+kc)*64 + l)*8 + e] = bf16(Whh[tile*16 + (l&15)][kc*32 + (l>>4)*8 + e])
__global__ __launch_bounds__(256) void wcvt_whh(const float* __restrict__ Whh,
                                                unsigned short* __restrict__ dst) {
    const int i = blockIdx.x * 256 + threadIdx.x;   // 0 .. 80*10*64-1
    if (i >= 80 * 10 * 64) return;
    const int l = i & 63;
    const int kc = (i >> 6) % 10;
    const int tile = i / 640;
    const int row = tile * 16 + (l & 15);
    const int k0 = kc * 32 + (l >> 4) * 8;
    const float* s = Whh + (size_t)row * HH + k0;
    const float4 v0 = *(const float4*)s;
    const float4 v1 = *(const float4*)(s + 4);
    unsigned short tmp[8] = { f2bf(v0.x), f2bf(v0.y), f2bf(v0.z), f2bf(v0.w),
                              f2bf(v1.x), f2bf(v1.y), f2bf(v1.z), f2bf(v1.w) };
    *(uint4*)(dst + (size_t)i * 8) = *(const uint4*)tmp;
}

// ---------------- Stage C: LSTM recurrence, 8 INDEPENDENT blocks (no inter-block sync) ----------------
// Block p owns batches [4p, 4p+4) and computes ALL 1280 gates per step:
// gates[4][1280] = Hl[4][320](bf16, LDS) @ Whh^T via MFMA (M=4 in 16x16 tiles),
// streaming the full 800KB bf16 Whhp from the XCD's L2 every step.
// h never leaves the block: cell writes Hl(LDS) + Hsb(global, for logits stage).
__global__ __launch_bounds__(1024) void stage_rec(const float* __restrict__ G,
                                                  const unsigned short* __restrict__ Whhp,
                                                  unsigned short* __restrict__ Hsb) {
    const int p = blockIdx.x;            // 0..7
    const int b0 = p * RB;
    const int tid = threadIdx.x;
    const int l = tid & 63, w = tid >> 6;   // 16 waves
    const int lr = l & 15;

    __shared__ unsigned short Hl[16][328];  // bf16 h; rows 4..15 stay zero (M-pad)
    __shared__ float Gl[RB][G4 + 8];        // MFMA gate outputs

    for (int i = tid; i < 16 * 328; i += 1024) ((unsigned short*)Hl)[i] = 0;

    // cell ownership: cell cid -> (m = cid/320, u = cid%320); thread does cid=tid
    // and (if tid<256) cid=1024+tid.
    const int m_a = tid / 320, u_a = tid - (tid / 320) * 320;
    const int cid_b = 1024 + tid;
    const int m_b = cid_b / 320, u_b = cid_b - (cid_b / 320) * 320;  // valid for tid<256
    const bool has_b = (tid < 256);
    float c_a = 0.f, c_b = 0.f;

    __syncthreads();

    for (int t = 0; t < TT; ++t) {
        // gate-input prefetch (independent of h; lands under the MFMA/stream phase)
        const float* gbase = G + (size_t)t * BB * G4;
        float ga[4], gb[4];
#pragma unroll
        for (int q = 0; q < 4; ++q) {
            ga[q] = gbase[(size_t)(b0 + m_a) * G4 + q * HH + u_a];
            gb[q] = has_b ? gbase[(size_t)(b0 + m_b) * G4 + q * HH + u_b] : 0.f;
        }

        if (t > 0) {
            // wave w computes n-tiles w*5 .. w*5+4 (80 tiles total), K=320 (10 frags)
            f32x4 acc[5] = {};
#pragma unroll
            for (int kc = 0; kc < 10; ++kc) {
                const bf16x8v av = *(const bf16x8v*)&Hl[lr][kc * 32 + (l >> 4) * 8];
#pragma unroll
                for (int j = 0; j < 5; ++j) {
                    const int tile = w * 5 + j;
                    const bf16x8v bv = *(const bf16x8v*)
                        (Whhp + ((size_t)(tile * 10 + kc) * 64 + l) * 8);  // coalesced 1KB/wave
                    acc[j] = __builtin_amdgcn_mfma_f32_16x16x32_bf16(av, bv, acc[j], 0, 0, 0);
                }
            }
            // C/D: col=lane&15 (gate-row in tile), row=(lane>>4)*4+reg (batch). Batches 0-3 in lanes 0-15.
            if (l < 16) {
#pragma unroll
                for (int j = 0; j < 5; ++j)
#pragma unroll
                    for (int rg = 0; rg < 4; ++rg)
                        Gl[rg][(w * 5 + j) * 16 + lr] = acc[j][rg];
            }
            __syncthreads();   // Gl ready
        }

        // cell phase
        {
            float a[4];
#pragma unroll
            for (int q = 0; q < 4; ++q)
                a[q] = ga[q] + (t > 0 ? Gl[m_a][q * HH + u_a] : 0.f);
            const float cn = fsigm(a[1]) * c_a + fsigm(a[0]) * ftanh(a[2]);
            const float hn = fsigm(a[3]) * ftanh(cn);
            c_a = cn;
            Hsb[((size_t)(b0 + m_a) * TT + t) * HH + u_a] = f2bf(hn);
            Hl[m_a][u_a] = f2bf(hn);
        }
        if (has_b) {
            float a[4];
#pragma unroll
            for (int q = 0; q < 4; ++q)
                a[q] = gb[q] + (t > 0 ? Gl[m_b][q * HH + u_b] : 0.f);
            const float cn = fsigm(a[1]) * c_b + fsigm(a[0]) * ftanh(a[2]);
            const float hn = fsigm(a[3]) * ftanh(cn);
            c_b = cn;
            Hsb[((size_t)(b0 + m_b) * TT + t) * HH + u_b] = f2bf(hn);
            Hl[m_b][u_b] = f2bf(hn);
        }
        __syncthreads();   // Hl ready for next step; Gl safe to overwrite (WAR)
    }
}

// ---------------- Stage D: MFMA bf16 GEMM: out[m][v] = Hsb[m,:] . Woutb[v,:] + bout[v] ----------------
__global__ __launch_bounds__(256, 2) void stage_logits_mfma(const unsigned short* __restrict__ A,
                                                            const unsigned short* __restrict__ Bm,
                                                            const float* __restrict__ bout,
                                                            float* __restrict__ out) {
    __shared__ unsigned short As[128][40];
    __shared__ unsigned short Bs[128][40];
    const int tid = threadIdx.x;
    const int m0 = blockIdx.y * 128;
    const int n0 = blockIdx.x * 128;
    const int w = tid >> 6, l = tid & 63;
    const int wr = w >> 1, wc = w & 1;
    const int lr = l & 15, lk = l >> 4;

    f32x4 acc[4][4] = {};
    for (int k0 = 0; k0 < HH; k0 += 32) {
#pragma unroll
        for (int i = 0; i < 2; ++i) {
            const int uidx = tid + 256 * i;
            const int rr = uidx >> 2, ss = uidx & 3;
            *(uint4*)&As[rr][ss * 8] = *(const uint4*)(A + (size_t)(m0 + rr) * HH + k0 + ss * 8);
            *(uint4*)&Bs[rr][ss * 8] = *(const uint4*)(Bm + (size_t)(n0 + rr) * HH + k0 + ss * 8);
        }
        __syncthreads();
        bf16x8v af[4], bfr[4];
#pragma unroll
        for (int f = 0; f < 4; ++f) {
            af[f]  = *(const bf16x8v*)&As[wr * 64 + f * 16 + lr][lk * 8];
            bfr[f] = *(const bf16x8v*)&Bs[wc * 64 + f * 16 + lr][lk * 8];
        }
#pragma unroll
        for (int fm = 0; fm < 4; ++fm)
#pragma unroll
            for (int fn = 0; fn < 4; ++fn)
                acc[fm][fn] = __builtin_amdgcn_mfma_f32_16x16x32_bf16(af[fm], bfr[fn], acc[fm][fn], 0, 0, 0);
        __syncthreads();
    }
#pragma unroll
    for (int fn = 0; fn < 4; ++fn) {
        const int n = n0 + wc * 64 + fn * 16 + lr;
        const float bv = bout[n];
#pragma unroll
        for (int fm = 0; fm < 4; ++fm) {
            const int mbase = m0 + wr * 64 + fm * 16 + lk * 4;
#pragma unroll
            for (int rg = 0; rg < 4; ++rg)
                out[(size_t)(mbase + rg) * VV + n] = acc[fm][fn][rg] + bv;
        }
    }
}

// ---------------- Stage E: in-place log_softmax over V per row ----------------
__global__ __launch_bounds__(256) void stage_lsm(float* __restrict__ out) {
    __shared__ float buf[VV];
    __shared__ float red[16];
    const size_t m = blockIdx.x;
    float4* row4 = (float4*)(out + m * VV);
    float4* buf4 = (float4*)buf;
    const int tid = threadIdx.x;

    float mx = -INFINITY;
    for (int k4 = tid; k4 < VV / 4; k4 += 256) {
        const float4 v = row4[k4];
        buf4[k4] = v;
        mx = fmaxf(mx, fmaxf(fmaxf(v.x, v.y), fmaxf(v.z, v.w)));
    }
#pragma unroll
    for (int off = 32; off > 0; off >>= 1) mx = fmaxf(mx, __shfl_down(mx, off, 64));
    if ((tid & 63) == 0) red[tid >> 6] = mx;
    __syncthreads();
    if (tid == 0) {
        float m2 = red[0];
        for (int i = 1; i < 4; ++i) m2 = fmaxf(m2, red[i]);
        red[0] = m2;
    }
    __syncthreads();
    mx = red[0];

    float s = 0.f;
    for (int k4 = tid; k4 < VV / 4; k4 += 256) {
        const float4 v = buf4[k4];
        s += __expf(v.x - mx) + __expf(v.y - mx) + __expf(v.z - mx) + __expf(v.w - mx);
    }
#pragma unroll
    for (int off = 32; off > 0; off >>= 1) s += __shfl_down(s, off, 64);
    if ((tid & 63) == 0) red[8 + (tid >> 6)] = s;
    __syncthreads();
    if (tid == 0) {
        float s2 = 0.f;
        for (int i = 0; i < 4; ++i) s2 += red[8 + i];
        red[8] = logf(s2);
    }
    __syncthreads();
    const float lse = mx + red[8];
    for (int k4 = tid; k4 < VV / 4; k4 += 256) {
        float4 v = buf4[k4];
        v.x -= lse; v.y -= lse; v.z -= lse; v.w -= lse;
        row4[k4] = v;
    }
}

extern "C" void kernel_launch(void* const* d_in, const int* in_sizes, int n_in,
                              void* d_out, int out_size, void* d_ws, size_t ws_size,
                              hipStream_t stream) {
    const float* ac   = (const float*)d_in[0];
    const int*   tok  = (const int*)d_in[1];
    const float* emb  = (const float*)d_in[2];
    const float* Win  = (const float*)d_in[3];
    const float* bin  = (const float*)d_in[4];
    const float* Wih  = (const float*)d_in[5];
    const float* Whh  = (const float*)d_in[6];
    const float* bih  = (const float*)d_in[7];
    const float* bhh  = (const float*)d_in[8];
    const float* Wout = (const float*)d_in[9];
    const float* bout = (const float*)d_in[10];
    float* out = (float*)d_out;

    float* X  = (float*)d_ws;                                   // [T*B,H] fp32, 21 MB
    float* G  = X + (size_t)TT * BB * HH;                       // [T*B,4H] fp32, 84 MB
    unsigned short* Hsb   = (unsigned short*)(G + (size_t)TT * BB * G4);  // [B][T][H] bf16
    unsigned short* Woutb = Hsb + (size_t)TT * BB * HH;         // [V][H] bf16
    unsigned short* Whhp  = Woutb + (size_t)VV * HH;            // [80][10][64][8] bf16, 800 KB

    stage_x<<<dim3(TT * BB / 8), dim3(320), 0, stream>>>(ac, tok, emb, Win, bin, X);
    stage_gin<<<dim3(TT * BB / 8), dim3(256), 0, stream>>>(X, Wih, bih, bhh, G);
    wcvt<<<dim3((VV * HH / 4 + 255) / 256), dim3(256), 0, stream>>>(Wout, Woutb, VV * HH / 4);
    wcvt_whh<<<dim3((80 * 10 * 64 + 255) / 256), dim3(256), 0, stream>>>(Whh, Whhp);
    stage_rec<<<dim3(8), dim3(1024), 0, stream>>>(G, Whhp, Hsb);
    stage_logits_mfma<<<dim3(VV / 128, TT * BB / 128), dim3(256), 0, stream>>>(Hsb, Woutb, bout, out);
    stage_lsm<<<dim3(TT * BB), dim3(256), 0, stream>>>(out);
}